// Round 5
// baseline (402.584 us; speedup 1.0000x reference)
//
#include <hip/hip_runtime.h>
#include <stdint.h>

// ---------------------------------------------------------------------------
// SelfAttention: out = softmax((x Wq^T)(x Wk^T)^T / sqrt(E)) (x Wv^T)
// B=4, S=2048, E=1024. bf16 MFMA, fp32 accumulate.
// R5: asymmetric GEMM feed — A-fragments loaded per-lane directly from
// global (L1/L2-hot, no LDS round-trip), B staged through a 3-stage LDS
// ring via global_load_lds. Halves LDS traffic (the R4 bottleneck: LDS pipe
// ~57% vs MFMA 35%). vmcnt discipline: A-loads issue BEFORE the gll16
// prefetch so the compiler's A-wait (vmcnt(2)) never drains the newest
// stage; barrier uses manual vmcnt(2) — never 0 mid-loop.
// ---------------------------------------------------------------------------

typedef __attribute__((ext_vector_type(8))) short bf16x8;   // 8 bf16 = 4 VGPRs
typedef __attribute__((ext_vector_type(4))) float f32x4;

__device__ __forceinline__ float bf2f(uint16_t u) {
    return __uint_as_float(((uint32_t)u) << 16);
}
__device__ __forceinline__ uint16_t f2bf(float f) {
    uint32_t u = __float_as_uint(f);
    uint32_t r = u + 0x7FFFu + ((u >> 16) & 1u);   // RNE
    return (uint16_t)(r >> 16);
}

// async global -> LDS, 16 bytes per lane (wave-uniform base + lane*16)
__device__ __forceinline__ void gll16(const void* g, void* l) {
    __builtin_amdgcn_global_load_lds(
        (const __attribute__((address_space(1))) uint32_t*)g,
        (__attribute__((address_space(3))) uint32_t*)l,
        16, 0, 0);
}

// ---- cast fp32 -> bf16, vectorized x4 -------------------------------------
__global__ __launch_bounds__(256) void cast_f32_bf16(const float* __restrict__ in,
                                                     uint16_t* __restrict__ out,
                                                     int n4) {
    int i = blockIdx.x * 256 + threadIdx.x;
    if (i < n4) {
        float4 v = ((const float4*)in)[i];
        ushort4 o;
        o.x = f2bf(v.x); o.y = f2bf(v.y); o.z = f2bf(v.z); o.w = f2bf(v.w);
        ((ushort4*)out)[i] = o;
    }
}

// ---- bf16 strided transpose: in[r][c] (stride istride) -> out[c][r] -------
__global__ __launch_bounds__(256) void transpose_bf16(const uint16_t* __restrict__ in,
                                                      uint16_t* __restrict__ out,
                                                      int rows, int cols, int istride,
                                                      long ibatch, long obatch) {
    __shared__ uint16_t tile[32][33];
    in  += (long)blockIdx.z * ibatch;
    out += (long)blockIdx.z * obatch;
    int bx = blockIdx.x * 32;   // col base
    int by = blockIdx.y * 32;   // row base
    int tx = threadIdx.x, ty = threadIdx.y;   // 32 x 8
    #pragma unroll
    for (int i = ty; i < 32; i += 8)
        tile[i][tx] = in[(long)(by + i) * istride + bx + tx];
    __syncthreads();
    #pragma unroll
    for (int i = ty; i < 32; i += 8)
        out[(long)(bx + i) * rows + by + tx] = tile[tx][i];
}

// ---- row softmax over 2048 bf16 elements, in place, one block per row -----
__global__ __launch_bounds__(256) void softmax_rows(uint16_t* __restrict__ P) {
    const int n = 2048;
    uint16_t* row = P + (size_t)blockIdx.x * n;
    int tid = threadIdx.x;
    int w = tid >> 6, ln = tid & 63;
    float v[8];
    float m = -3.4e38f;
    #pragma unroll
    for (int i = 0; i < 8; i++) { v[i] = bf2f(row[tid + 256 * i]); m = fmaxf(m, v[i]); }
    #pragma unroll
    for (int o = 32; o >= 1; o >>= 1) m = fmaxf(m, __shfl_down(m, o, 64));
    __shared__ float smax[4], ssum[4];
    if (ln == 0) smax[w] = m;
    __syncthreads();
    m = fmaxf(fmaxf(smax[0], smax[1]), fmaxf(smax[2], smax[3]));
    float s = 0.f;
    #pragma unroll
    for (int i = 0; i < 8; i++) { v[i] = __expf(v[i] - m); s += v[i]; }
    #pragma unroll
    for (int o = 32; o >= 1; o >>= 1) s += __shfl_down(s, o, 64);
    if (ln == 0) ssum[w] = s;
    __syncthreads();
    s = ssum[0] + ssum[1] + ssum[2] + ssum[3];
    float inv = 1.f / s;
    #pragma unroll
    for (int i = 0; i < 8; i++) row[tid + 256 * i] = f2bf(v[i] * inv);
}

// ---- NT GEMM: C[M][N] = alpha * A[M][K] * B[N][K]^T  (bf16 in, OutT out) --
// 128x128 tile, BK=32, 4 waves, 4x4 mfma_f32_16x16x32_bf16 per wave.
// A: per-lane direct global b128 loads (no LDS). B: 3-stage LDS ring via
// global_load_lds w16. 1D grid, XCD-contiguous swizzle + 8x8 supertiles.
// gx, gy must be multiples of 8 / grid divisible by 8 (all call sites ok).
#define BM 128
#define BN 128
#define BK 32

template <typename OutT>
__global__ __launch_bounds__(256) void gemm_nt(const uint16_t* __restrict__ A,
                                               const uint16_t* __restrict__ B,
                                               OutT* __restrict__ C,
                                               int gx, int gy,
                                               long lda, long ldb, long ldc,
                                               int K, float alpha,
                                               long sA, long sB, long sC) {
    // ---- XCD-contiguous swizzle + 8x8 supertile decode ----
    const int total = gridDim.x;
    const int n     = blockIdx.x;
    const int per   = total >> 3;
    const int g     = (n & 7) * per + (n >> 3);    // contiguous range per XCD
    const int pb    = gx * gy;                     // blocks per batch (z)
    const int bz    = g / pb;
    const int r     = g - bz * pb;
    const int stpr  = gx >> 3;                     // supertiles per row-band
    const int st    = r >> 6;
    const int w     = r & 63;
    const int sty   = st / stpr;
    const int stx   = st - sty * stpr;
    const int bx    = (stx << 3) + (w & 7);
    const int by    = (sty << 3) + (w >> 3);

    A += (long)bz * sA;
    B += (long)bz * sB;
    C += (long)bz * sC;

    __shared__ uint16_t Bs[3][BN * BK];   // 3 x 8 KB (B only)

    const int tid  = threadIdx.x;
    const int m0   = by * BM;
    const int n0   = bx * BN;
    const int wave = tid >> 6;
    const int lane = tid & 63;
    const int quad = lane >> 4;
    const int l16  = lane & 15;
    const int wr   = (wave >> 1) * 64;   // wave row offset in tile
    const int wc   = (wave & 1) * 64;    // wave col offset in tile

    // ---- B staging: each wave covers 2 groups of 16 rows (2 gll16/iter) ---
    // group gB: lane reads B row n0 + gB*16 + (lane>>2), 16 B at col (lane&3)*8
    const int gB0 = 2 * wave;
    const uint16_t* Bg0 = B + (long)(n0 + gB0 * 16 + (lane >> 2)) * ldb + (lane & 3) * 8;
    const uint16_t* Bg1 = Bg0 + 16 * ldb;
    // wave-uniform LDS element offsets within a slot (hw adds lane*16 B)
    const int bo0 = gB0 * 512;          // group g starts at g*16*32 elements
    const int bo1 = bo0 + 512;

    // ---- A direct: lane's fragment row ptrs, 16 B at k-offset quad*8 ------
    const uint16_t* Ap[4];
    #pragma unroll
    for (int i = 0; i < 4; i++)
        Ap[i] = A + (long)(m0 + wr + i * 16 + l16) * lda + quad * 8;

    const int nk = K / BK;

    // prologue: stage B slots 0 and 1 (4 gll16 per wave in flight)
    gll16(Bg0, &Bs[0][bo0]);
    gll16(Bg1, &Bs[0][bo1]);
    gll16(Bg0 + BK, &Bs[1][bo0]);
    gll16(Bg1 + BK, &Bs[1][bo1]);

    f32x4 acc[4][4] = {};
    int cur = 0, pf = 2;
    long kb = 2 * BK;   // next B k-offset to prefetch

    for (int k = 0; k < nk; ++k) {
        // retire the slot we consume (oldest); keep newest stage in flight
        asm volatile("s_waitcnt vmcnt(2)\n\ts_barrier" ::: "memory");

        // A-fragment loads FIRST (older than the gll16 below, so the
        // compiler's A-wait keeps the new prefetch outstanding)
        bf16x8 af[4];
        #pragma unroll
        for (int i = 0; i < 4; i++)
            af[i] = *(const bf16x8*)(Ap[i]);
        #pragma unroll
        for (int i = 0; i < 4; i++)
            Ap[i] += BK;

        if (k + 2 < nk) {
            gll16(Bg0 + kb, &Bs[pf][bo0]);
            gll16(Bg1 + kb, &Bs[pf][bo1]);
            kb += BK;
        }

        const uint16_t* Bc = Bs[cur];
        const int ko = quad * 8;
        bf16x8 bfr[4];
        #pragma unroll
        for (int j = 0; j < 4; j++)
            bfr[j] = *(const bf16x8*)(&Bc[(wc + j * 16 + l16) * BK + ko]);
        #pragma unroll
        for (int i = 0; i < 4; i++)
            #pragma unroll
            for (int j = 0; j < 4; j++)
                acc[i][j] = __builtin_amdgcn_mfma_f32_16x16x32_bf16(af[i], bfr[j], acc[i][j], 0, 0, 0);

        cur = (cur == 2) ? 0 : cur + 1;
        pf  = (pf  == 2) ? 0 : pf + 1;
    }

    // epilogue: C/D layout col = lane&15, row = quad*4 + reg
    #pragma unroll
    for (int i = 0; i < 4; i++) {
        #pragma unroll
        for (int j = 0; j < 4; j++) {
            #pragma unroll
            for (int r4 = 0; r4 < 4; r4++) {
                int row = m0 + wr + i * 16 + quad * 4 + r4;
                int col = n0 + wc + j * 16 + l16;
                float val = acc[i][j][r4] * alpha;
                if constexpr (sizeof(OutT) == 2)
                    C[(long)row * ldc + col] = f2bf(val);
                else
                    C[(long)row * ldc + col] = val;
            }
        }
    }
}

// ---------------------------------------------------------------------------
extern "C" void kernel_launch(void* const* d_in, const int* in_sizes, int n_in,
                              void* d_out, int out_size, void* d_ws, size_t ws_size,
                              hipStream_t stream) {
    const float* x  = (const float*)d_in[0];
    const float* Wq = (const float*)d_in[1];
    const float* Wk = (const float*)d_in[2];
    const float* Wv = (const float*)d_in[3];
    float* out = (float*)d_out;

    const int Bn = 4, S = 2048, E = 1024;
    const long MS = (long)Bn * S;              // 8192 total rows
    const int  N3 = 3 * E;                     // 3072

    // workspace layout (bf16), 118 MB total
    char* ws = (char*)d_ws;
    uint16_t* xb    = (uint16_t*)ws;  ws += (size_t)MS * E * 2;        // 16 MB
    uint16_t* wqkvb = (uint16_t*)ws;  ws += (size_t)N3 * E * 2;        //  6 MB
    uint16_t* QKVb  = (uint16_t*)ws;  ws += (size_t)MS * N3 * 2;       // 48 MB
    uint16_t* Pb    = (uint16_t*)ws;  ws += (size_t)Bn * S * S * 2;    // 32 MB
    uint16_t* Vt    = (uint16_t*)ws;  ws += (size_t)Bn * E * S * 2;    // 16 MB

    dim3 blk(256);

    // 1) casts to bf16 (W stacked [Wq;Wk;Wv] -> [3072][1024])
    {
        int n4 = (int)(MS * E / 4);
        cast_f32_bf16<<<dim3((n4 + 255) / 256), blk, 0, stream>>>(x, xb, n4);
        int n4w = E * E / 4;
        dim3 gw((n4w + 255) / 256);
        cast_f32_bf16<<<gw, blk, 0, stream>>>(Wq, wqkvb,             n4w);
        cast_f32_bf16<<<gw, blk, 0, stream>>>(Wk, wqkvb + (size_t)E * E,     n4w);
        cast_f32_bf16<<<gw, blk, 0, stream>>>(Wv, wqkvb + (size_t)2 * E * E, n4w);
    }

    // 2) fused QKV: QKVb[M][3072] = xb[M][1024] * wqkvb[3072][1024]^T
    {
        int gx = N3 / BN, gy = (int)(MS / BM);   // 24 x 64
        gemm_nt<uint16_t><<<dim3(gx * gy), blk, 0, stream>>>(
            xb, wqkvb, QKVb, gx, gy, E, E, N3, E, 1.f, 0, 0, 0);
    }

    // 3) Vt[b][e][s] = V[b][s][e]  (V = QKVb cols [2048,3072))
    transpose_bf16<<<dim3(E / 32, S / 32, Bn), dim3(32, 8), 0, stream>>>(
        QKVb + 2 * E, Vt, S, E, N3, (long)S * N3, (long)E * S);

    // 4) scores = (Q K^T) / sqrt(E) per batch, bf16 out
    {
        int gx = S / BN, gy = S / BM;            // 16 x 16, z=4
        gemm_nt<uint16_t><<<dim3(gx * gy * Bn), blk, 0, stream>>>(
            QKVb, QKVb + E, Pb, gx, gy, N3, N3, S, E, 0.03125f,
            (long)S * N3, (long)S * N3, (long)S * S);
    }

    // 5) softmax rows in place (4*2048 rows of 2048)
    softmax_rows<<<dim3(Bn * S), blk, 0, stream>>>(Pb);

    // 6) out = P * Vt^T  (M=2048, N=1024, K=2048 per batch), fp32 out
    {
        int gx = E / BN, gy = S / BM;            // 8 x 16, z=4
        gemm_nt<float><<<dim3(gx * gy * Bn), blk, 0, stream>>>(
            Pb, Vt, out, gx, gy, S, S, E, S, 1.f,
            (long)S * S, (long)E * S, (long)S * E);
    }
}

// Round 6
// 393.863 us; speedup vs baseline: 1.0221x; 1.0221x over previous
//
#include <hip/hip_runtime.h>
#include <stdint.h>

// ---------------------------------------------------------------------------
// SelfAttention: out = softmax((x Wq^T)(x Wk^T)^T / sqrt(E)) (x Wv^T)
// B=4, S=2048, E=1024. bf16 MFMA, fp32 accumulate.
// R6: R5's asymmetric feed (A direct from global, B via 3-stage LDS ring)
// + REGISTER PREFETCH for A (distance 1) — fixes R5's exposed A latency.
// vmcnt discipline: every iter issues exactly [4 A-loads, 2 gll16]; barrier
// waits vmcnt(6) = retire only the B slot being consumed. Tail iters issue
// clamped dummy loads to keep counts uniform.
// ---------------------------------------------------------------------------

typedef __attribute__((ext_vector_type(8))) short bf16x8;   // 8 bf16 = 4 VGPRs
typedef __attribute__((ext_vector_type(4))) float f32x4;

__device__ __forceinline__ float bf2f(uint16_t u) {
    return __uint_as_float(((uint32_t)u) << 16);
}
__device__ __forceinline__ uint16_t f2bf(float f) {
    uint32_t u = __float_as_uint(f);
    uint32_t r = u + 0x7FFFu + ((u >> 16) & 1u);   // RNE
    return (uint16_t)(r >> 16);
}

// async global -> LDS, 16 bytes per lane (wave-uniform base + lane*16)
__device__ __forceinline__ void gll16(const void* g, void* l) {
    __builtin_amdgcn_global_load_lds(
        (const __attribute__((address_space(1))) uint32_t*)g,
        (__attribute__((address_space(3))) uint32_t*)l,
        16, 0, 0);
}

// ---- cast fp32 -> bf16, vectorized x4 -------------------------------------
__global__ __launch_bounds__(256) void cast_f32_bf16(const float* __restrict__ in,
                                                     uint16_t* __restrict__ out,
                                                     int n4) {
    int i = blockIdx.x * 256 + threadIdx.x;
    if (i < n4) {
        float4 v = ((const float4*)in)[i];
        ushort4 o;
        o.x = f2bf(v.x); o.y = f2bf(v.y); o.z = f2bf(v.z); o.w = f2bf(v.w);
        ((ushort4*)out)[i] = o;
    }
}

// ---- bf16 strided transpose: in[r][c] (stride istride) -> out[c][r] -------
__global__ __launch_bounds__(256) void transpose_bf16(const uint16_t* __restrict__ in,
                                                      uint16_t* __restrict__ out,
                                                      int rows, int cols, int istride,
                                                      long ibatch, long obatch) {
    __shared__ uint16_t tile[32][33];
    in  += (long)blockIdx.z * ibatch;
    out += (long)blockIdx.z * obatch;
    int bx = blockIdx.x * 32;   // col base
    int by = blockIdx.y * 32;   // row base
    int tx = threadIdx.x, ty = threadIdx.y;   // 32 x 8
    #pragma unroll
    for (int i = ty; i < 32; i += 8)
        tile[i][tx] = in[(long)(by + i) * istride + bx + tx];
    __syncthreads();
    #pragma unroll
    for (int i = ty; i < 32; i += 8)
        out[(long)(bx + i) * rows + by + tx] = tile[tx][i];
}

// ---- row softmax over 2048 bf16 elements, in place, one block per row -----
__global__ __launch_bounds__(256) void softmax_rows(uint16_t* __restrict__ P) {
    const int n = 2048;
    uint16_t* row = P + (size_t)blockIdx.x * n;
    int tid = threadIdx.x;
    int w = tid >> 6, ln = tid & 63;
    float v[8];
    float m = -3.4e38f;
    #pragma unroll
    for (int i = 0; i < 8; i++) { v[i] = bf2f(row[tid + 256 * i]); m = fmaxf(m, v[i]); }
    #pragma unroll
    for (int o = 32; o >= 1; o >>= 1) m = fmaxf(m, __shfl_down(m, o, 64));
    __shared__ float smax[4], ssum[4];
    if (ln == 0) smax[w] = m;
    __syncthreads();
    m = fmaxf(fmaxf(smax[0], smax[1]), fmaxf(smax[2], smax[3]));
    float s = 0.f;
    #pragma unroll
    for (int i = 0; i < 8; i++) { v[i] = __expf(v[i] - m); s += v[i]; }
    #pragma unroll
    for (int o = 32; o >= 1; o >>= 1) s += __shfl_down(s, o, 64);
    if (ln == 0) ssum[w] = s;
    __syncthreads();
    s = ssum[0] + ssum[1] + ssum[2] + ssum[3];
    float inv = 1.f / s;
    #pragma unroll
    for (int i = 0; i < 8; i++) row[tid + 256 * i] = f2bf(v[i] * inv);
}

// ---- NT GEMM: C[M][N] = alpha * A[M][K] * B[N][K]^T  (bf16 in, OutT out) --
// 128x128 tile, BK=32, 4 waves, 4x4 mfma_f32_16x16x32_bf16 per wave.
// A: per-lane direct global b128 loads, REGISTER-PREFETCHED 1 iter ahead.
// B: 3-stage LDS ring via global_load_lds w16, prefetch distance 2.
// 1D grid, XCD-contiguous swizzle + 8x8 supertiles.
#define BM 128
#define BN 128
#define BK 32

template <typename OutT>
__global__ __launch_bounds__(256) void gemm_nt(const uint16_t* __restrict__ A,
                                               const uint16_t* __restrict__ B,
                                               OutT* __restrict__ C,
                                               int gx, int gy,
                                               long lda, long ldb, long ldc,
                                               int K, float alpha,
                                               long sA, long sB, long sC) {
    // ---- XCD-contiguous swizzle + 8x8 supertile decode ----
    const int total = gridDim.x;
    const int n     = blockIdx.x;
    const int per   = total >> 3;
    const int g     = (n & 7) * per + (n >> 3);    // contiguous range per XCD
    const int pb    = gx * gy;                     // blocks per batch (z)
    const int bz    = g / pb;
    const int r     = g - bz * pb;
    const int stpr  = gx >> 3;                     // supertiles per row-band
    const int st    = r >> 6;
    const int w     = r & 63;
    const int sty   = st / stpr;
    const int stx   = st - sty * stpr;
    const int bx    = (stx << 3) + (w & 7);
    const int by    = (sty << 3) + (w >> 3);

    A += (long)bz * sA;
    B += (long)bz * sB;
    C += (long)bz * sC;

    __shared__ uint16_t Bs[3][BN * BK];   // 3 x 8 KB (B only)

    const int tid  = threadIdx.x;
    const int m0   = by * BM;
    const int n0   = bx * BN;
    const int wave = tid >> 6;
    const int lane = tid & 63;
    const int quad = lane >> 4;
    const int l16  = lane & 15;
    const int wr   = (wave >> 1) * 64;   // wave row offset in tile
    const int wc   = (wave & 1) * 64;    // wave col offset in tile

    // ---- B staging: each wave covers 2 groups of 16 rows (2 gll16/iter) ---
    const int gB0 = 2 * wave;
    const uint16_t* Bg0 = B + (long)(n0 + gB0 * 16 + (lane >> 2)) * ldb + (lane & 3) * 8;
    const uint16_t* Bg1 = Bg0 + 16 * ldb;
    const int bo0 = gB0 * 512;          // wave-uniform slot offsets (elements)
    const int bo1 = bo0 + 512;

    // ---- A direct: lane's fragment row base ptrs (k added per iter) -------
    const uint16_t* Arow[4];
    #pragma unroll
    for (int i = 0; i < 4; i++)
        Arow[i] = A + (long)(m0 + wr + i * 16 + l16) * lda + quad * 8;

    const int nk = K / BK;

    // prologue: stage B slots 0,1 (4 gll16), then A-frags for k=0 (4 loads)
    gll16(Bg0,      &Bs[0][bo0]);
    gll16(Bg1,      &Bs[0][bo1]);
    gll16(Bg0 + BK, &Bs[1][bo0]);
    gll16(Bg1 + BK, &Bs[1][bo1]);
    bf16x8 af[4];
    #pragma unroll
    for (int i = 0; i < 4; i++)
        af[i] = *(const bf16x8*)(Arow[i]);

    f32x4 acc[4][4] = {};
    int cur = 0, pf = 2;

    for (int k = 0; k < nk; ++k) {
        // Retire exactly the B slot we are about to consume (its 2 gll16 are
        // the oldest outstanding); keep the newest 6 (4 A + 2 gll16) in
        // flight across the barrier. Constant valid for all k (tail issues
        // clamped dummy loads to keep counts uniform).
        asm volatile("s_waitcnt vmcnt(6)\n\ts_barrier" ::: "memory");

        // A register prefetch for k+1 (clamped dummy on last iter)
        const long ka = (k + 1 < nk) ? (long)(k + 1) * BK : 0;
        bf16x8 an[4];
        #pragma unroll
        for (int i = 0; i < 4; i++)
            an[i] = *(const bf16x8*)(Arow[i] + ka);

        // B LDS prefetch for k+2 (clamped dummy in tail; dummy targets the
        // pf slot which is provably not the slot being read this iter)
        const long kb = (k + 2 < nk) ? (long)(k + 2) * BK : 0;
        gll16(Bg0 + kb, &Bs[pf][bo0]);
        gll16(Bg1 + kb, &Bs[pf][bo1]);

        const uint16_t* Bc = Bs[cur];
        const int ko = quad * 8;
        bf16x8 bfr[4];
        #pragma unroll
        for (int j = 0; j < 4; j++)
            bfr[j] = *(const bf16x8*)(&Bc[(wc + j * 16 + l16) * BK + ko]);
        #pragma unroll
        for (int i = 0; i < 4; i++)
            #pragma unroll
            for (int j = 0; j < 4; j++)
                acc[i][j] = __builtin_amdgcn_mfma_f32_16x16x32_bf16(af[i], bfr[j], acc[i][j], 0, 0, 0);

        #pragma unroll
        for (int i = 0; i < 4; i++)
            af[i] = an[i];

        cur = (cur == 2) ? 0 : cur + 1;
        pf  = (pf  == 2) ? 0 : pf + 1;
    }

    // epilogue: C/D layout col = lane&15, row = quad*4 + reg
    #pragma unroll
    for (int i = 0; i < 4; i++) {
        #pragma unroll
        for (int j = 0; j < 4; j++) {
            #pragma unroll
            for (int r4 = 0; r4 < 4; r4++) {
                int row = m0 + wr + i * 16 + quad * 4 + r4;
                int col = n0 + wc + j * 16 + l16;
                float val = acc[i][j][r4] * alpha;
                if constexpr (sizeof(OutT) == 2)
                    C[(long)row * ldc + col] = f2bf(val);
                else
                    C[(long)row * ldc + col] = val;
            }
        }
    }
}

// ---------------------------------------------------------------------------
extern "C" void kernel_launch(void* const* d_in, const int* in_sizes, int n_in,
                              void* d_out, int out_size, void* d_ws, size_t ws_size,
                              hipStream_t stream) {
    const float* x  = (const float*)d_in[0];
    const float* Wq = (const float*)d_in[1];
    const float* Wk = (const float*)d_in[2];
    const float* Wv = (const float*)d_in[3];
    float* out = (float*)d_out;

    const int Bn = 4, S = 2048, E = 1024;
    const long MS = (long)Bn * S;              // 8192 total rows
    const int  N3 = 3 * E;                     // 3072

    // workspace layout (bf16), 118 MB total
    char* ws = (char*)d_ws;
    uint16_t* xb    = (uint16_t*)ws;  ws += (size_t)MS * E * 2;        // 16 MB
    uint16_t* wqkvb = (uint16_t*)ws;  ws += (size_t)N3 * E * 2;        //  6 MB
    uint16_t* QKVb  = (uint16_t*)ws;  ws += (size_t)MS * N3 * 2;       // 48 MB
    uint16_t* Pb    = (uint16_t*)ws;  ws += (size_t)Bn * S * S * 2;    // 32 MB
    uint16_t* Vt    = (uint16_t*)ws;  ws += (size_t)Bn * E * S * 2;    // 16 MB

    dim3 blk(256);

    // 1) casts to bf16 (W stacked [Wq;Wk;Wv] -> [3072][1024])
    {
        int n4 = (int)(MS * E / 4);
        cast_f32_bf16<<<dim3((n4 + 255) / 256), blk, 0, stream>>>(x, xb, n4);
        int n4w = E * E / 4;
        dim3 gw((n4w + 255) / 256);
        cast_f32_bf16<<<gw, blk, 0, stream>>>(Wq, wqkvb,             n4w);
        cast_f32_bf16<<<gw, blk, 0, stream>>>(Wk, wqkvb + (size_t)E * E,     n4w);
        cast_f32_bf16<<<gw, blk, 0, stream>>>(Wv, wqkvb + (size_t)2 * E * E, n4w);
    }

    // 2) fused QKV: QKVb[M][3072] = xb[M][1024] * wqkvb[3072][1024]^T
    {
        int gx = N3 / BN, gy = (int)(MS / BM);   // 24 x 64
        gemm_nt<uint16_t><<<dim3(gx * gy), blk, 0, stream>>>(
            xb, wqkvb, QKVb, gx, gy, E, E, N3, E, 1.f, 0, 0, 0);
    }

    // 3) Vt[b][e][s] = V[b][s][e]  (V = QKVb cols [2048,3072))
    transpose_bf16<<<dim3(E / 32, S / 32, Bn), dim3(32, 8), 0, stream>>>(
        QKVb + 2 * E, Vt, S, E, N3, (long)S * N3, (long)E * S);

    // 4) scores = (Q K^T) / sqrt(E) per batch, bf16 out
    {
        int gx = S / BN, gy = S / BM;            // 16 x 16, z=4
        gemm_nt<uint16_t><<<dim3(gx * gy * Bn), blk, 0, stream>>>(
            QKVb, QKVb + E, Pb, gx, gy, N3, N3, S, E, 0.03125f,
            (long)S * N3, (long)S * N3, (long)S * S);
    }

    // 5) softmax rows in place (4*2048 rows of 2048)
    softmax_rows<<<dim3(Bn * S), blk, 0, stream>>>(Pb);

    // 6) out = P * Vt^T  (M=2048, N=1024, K=2048 per batch), fp32 out
    {
        int gx = E / BN, gy = S / BM;            // 8 x 16, z=4
        gemm_nt<float><<<dim3(gx * gy * Bn), blk, 0, stream>>>(
            Pb, Vt, out, gx, gy, S, S, E, S, 1.f,
            (long)S * S, (long)E * S, (long)S * E);
    }
}

// Round 7
// 264.616 us; speedup vs baseline: 1.5214x; 1.4884x over previous
//
#include <hip/hip_runtime.h>
#include <stdint.h>

// ---------------------------------------------------------------------------
// SelfAttention: out = softmax((x Wq^T)(x Wk^T)^T / sqrt(E)) (x Wv^T)
// B=4, S=2048, E=1024. bf16 MFMA, fp32 accumulate.
// R7: revert to R4's all-LDS 3-stage ring GEMM (best measured). New:
//  - single fused cast kernel (was 4 dispatches)
//  - QKV epilogue writes V directly TRANSPOSED to Vt (packed ushort4 stores;
//    kills the transpose dispatch + V round-trip), Q/K into QKb ld=2048.
// Dispatches: cast, QKV, scores, softmax, PV  (was 9).
// ---------------------------------------------------------------------------

typedef __attribute__((ext_vector_type(8))) short bf16x8;   // 8 bf16 = 4 VGPRs
typedef __attribute__((ext_vector_type(4))) float f32x4;

__device__ __forceinline__ float bf2f(uint16_t u) {
    return __uint_as_float(((uint32_t)u) << 16);
}
__device__ __forceinline__ uint16_t f2bf(float f) {
    uint32_t u = __float_as_uint(f);
    uint32_t r = u + 0x7FFFu + ((u >> 16) & 1u);   // RNE
    return (uint16_t)(r >> 16);
}

// async global -> LDS, 16 bytes per lane (wave-uniform base + lane*16)
__device__ __forceinline__ void gll16(const void* g, void* l) {
    __builtin_amdgcn_global_load_lds(
        (const __attribute__((address_space(1))) uint32_t*)g,
        (__attribute__((address_space(3))) uint32_t*)l,
        16, 0, 0);
}

// ---- fused cast: x (NX4 float4s) then stacked Wq|Wk|Wv (NW4 each) ---------
__global__ __launch_bounds__(256) void cast_all(const float* __restrict__ x,
                                                const float* __restrict__ Wq,
                                                const float* __restrict__ Wk,
                                                const float* __restrict__ Wv,
                                                uint16_t* __restrict__ xb,
                                                uint16_t* __restrict__ wqkvb,
                                                int NX4, int NW4) {
    int i = blockIdx.x * 256 + threadIdx.x;
    const float* src;
    uint16_t* dst;
    int off;
    if (i < NX4) {
        src = x; dst = xb; off = i;
    } else {
        int j = i - NX4;
        if (j >= 3 * NW4) return;
        int which = j / NW4;              // 0,1,2
        off = j - which * NW4;
        src = (which == 0) ? Wq : (which == 1) ? Wk : Wv;
        dst = wqkvb + (size_t)which * NW4 * 4;
    }
    float4 v = ((const float4*)src)[off];
    ushort4 o;
    o.x = f2bf(v.x); o.y = f2bf(v.y); o.z = f2bf(v.z); o.w = f2bf(v.w);
    ((ushort4*)dst)[off] = o;
}

// ---- row softmax over 2048 bf16 elements, in place, one block per row -----
__global__ __launch_bounds__(256) void softmax_rows(uint16_t* __restrict__ P) {
    const int n = 2048;
    uint16_t* row = P + (size_t)blockIdx.x * n;
    int tid = threadIdx.x;
    int w = tid >> 6, ln = tid & 63;
    float v[8];
    float m = -3.4e38f;
    #pragma unroll
    for (int i = 0; i < 8; i++) { v[i] = bf2f(row[tid + 256 * i]); m = fmaxf(m, v[i]); }
    #pragma unroll
    for (int o = 32; o >= 1; o >>= 1) m = fmaxf(m, __shfl_down(m, o, 64));
    __shared__ float smax[4], ssum[4];
    if (ln == 0) smax[w] = m;
    __syncthreads();
    m = fmaxf(fmaxf(smax[0], smax[1]), fmaxf(smax[2], smax[3]));
    float s = 0.f;
    #pragma unroll
    for (int i = 0; i < 8; i++) { v[i] = __expf(v[i] - m); s += v[i]; }
    #pragma unroll
    for (int o = 32; o >= 1; o >>= 1) s += __shfl_down(s, o, 64);
    if (ln == 0) ssum[w] = s;
    __syncthreads();
    s = ssum[0] + ssum[1] + ssum[2] + ssum[3];
    float inv = 1.f / s;
    #pragma unroll
    for (int i = 0; i < 8; i++) row[tid + 256 * i] = f2bf(v[i] * inv);
}

// ---- NT GEMM: C[M][N] = alpha * A[M][K] * B[N][K]^T  (bf16 in, OutT out) --
// 128x128 tile, BK=32, 4 waves, 4x4 mfma_f32_16x16x32_bf16 per wave.
// 3-stage LDS ring, global_load_lds w16, vmcnt(4)+barrier (depth-2 prefetch,
// newest stage stays in flight across the barrier). 1D grid, XCD-contiguous
// swizzle + 8x8 supertiles. Optional: columns >= vcol0 are written
// TRANSPOSED into Vt[b][col-vcol0][row%2048] as packed ushort4 (V output).
#define BM 128
#define BN 128
#define BK 32

template <typename OutT>
__global__ __launch_bounds__(256) void gemm_nt(const uint16_t* __restrict__ A,
                                               const uint16_t* __restrict__ B,
                                               OutT* __restrict__ C,
                                               int gx, int gy,
                                               long lda, long ldb, long ldc,
                                               int K, float alpha,
                                               long sA, long sB, long sC,
                                               uint16_t* __restrict__ VtP,
                                               int vcol0) {
    // ---- XCD-contiguous swizzle + 8x8 supertile decode ----
    const int total = gridDim.x;
    const int n     = blockIdx.x;
    const int per   = total >> 3;
    const int g     = (n & 7) * per + (n >> 3);    // contiguous range per XCD
    const int pb    = gx * gy;                     // blocks per batch (z)
    const int bz    = g / pb;
    const int r     = g - bz * pb;
    const int stpr  = gx >> 3;                     // supertiles per row-band
    const int st    = r >> 6;
    const int w     = r & 63;
    const int sty   = st / stpr;
    const int stx   = st - sty * stpr;
    const int bx    = (stx << 3) + (w & 7);
    const int by    = (sty << 3) + (w >> 3);

    A += (long)bz * sA;
    B += (long)bz * sB;
    C += (long)bz * sC;

    __shared__ uint16_t As[3][BM * BK];   // 3 x 8 KB
    __shared__ uint16_t Bs[3][BM * BK];   // 3 x 8 KB

    const int tid  = threadIdx.x;
    const int m0   = by * BM;
    const int n0   = bx * BN;
    const int wave = tid >> 6;
    const int lane = tid & 63;
    const int quad = lane >> 4;
    const int l16  = lane & 15;
    const int wr   = (wave >> 1) * 64;   // wave row offset in tile
    const int wc   = (wave & 1) * 64;    // wave col offset in tile

    // staging: thread covers row sr (+64), 8 bf16 (16 B) at col sc
    const int sr = tid >> 2;            // 0..63
    const int sc = (tid & 3) * 8;       // 0,8,16,24
    const uint16_t* Ag = A + (long)(m0 + sr) * lda + sc;
    const uint16_t* Bg = B + (long)(n0 + sr) * ldb + sc;
    const long rsA = 64 * lda;
    const long rsB = 64 * ldb;
    const int so0 = sr * BK + sc;
    const int so1 = (sr + 64) * BK + sc;

    const int nk = K / BK;

    // prologue: prefetch tiles 0 and 1 into slots 0 and 1 (8 loads in flight)
    gll16(Ag,       &As[0][so0]);
    gll16(Ag + rsA, &As[0][so1]);
    gll16(Bg,       &Bs[0][so0]);
    gll16(Bg + rsB, &Bs[0][so1]);
    Ag += BK; Bg += BK;
    gll16(Ag,       &As[1][so0]);
    gll16(Ag + rsA, &As[1][so1]);
    gll16(Bg,       &Bs[1][so0]);
    gll16(Bg + rsB, &Bs[1][so1]);
    Ag += BK; Bg += BK;

    f32x4 acc[4][4] = {};
    int cur = 0, pf = 2;

    for (int k = 0; k < nk; ++k) {
        // retire only the tile we are about to consume (its 4 loads are the
        // oldest); keep the newest 4 in flight across the barrier.
        if (k < nk - 1) {
            asm volatile("s_waitcnt vmcnt(4)\n\ts_barrier" ::: "memory");
        } else {
            asm volatile("s_waitcnt vmcnt(0)\n\ts_barrier" ::: "memory");
        }

        if (k + 2 < nk) {
            gll16(Ag,       &As[pf][so0]);
            gll16(Ag + rsA, &As[pf][so1]);
            gll16(Bg,       &Bs[pf][so0]);
            gll16(Bg + rsB, &Bs[pf][so1]);
            Ag += BK; Bg += BK;
        }

        const uint16_t* Ac = As[cur];
        const uint16_t* Bc = Bs[cur];
        const int ko = quad * 8;
        bf16x8 af[4], bfr[4];
        #pragma unroll
        for (int i = 0; i < 4; i++)
            af[i] = *(const bf16x8*)(&Ac[(wr + i * 16 + l16) * BK + ko]);
        #pragma unroll
        for (int j = 0; j < 4; j++)
            bfr[j] = *(const bf16x8*)(&Bc[(wc + j * 16 + l16) * BK + ko]);
        #pragma unroll
        for (int i = 0; i < 4; i++)
            #pragma unroll
            for (int j = 0; j < 4; j++)
                acc[i][j] = __builtin_amdgcn_mfma_f32_16x16x32_bf16(af[i], bfr[j], acc[i][j], 0, 0, 0);

        cur = (cur == 2) ? 0 : cur + 1;
        pf  = (pf  == 2) ? 0 : pf + 1;
    }

    // ---- epilogue: C/D layout col = lane&15, row = quad*4 + reg ----
    if (VtP && n0 >= vcol0) {
        // V region: write transposed, Vt[b][e][s], e = col - vcol0,
        // b = row>>11, s = row&2047. 4 consecutive rows (r4) per lane are
        // contiguous in s -> one packed ushort4 (8 B) store per (i,j).
        #pragma unroll
        for (int i = 0; i < 4; i++) {
            const int row0 = m0 + wr + i * 16 + quad * 4;
            const int b    = row0 >> 11;
            const int s    = row0 & 2047;
            #pragma unroll
            for (int j = 0; j < 4; j++) {
                const int e = n0 + wc + j * 16 + l16 - vcol0;
                ushort4 o;
                o.x = f2bf(acc[i][j][0]);
                o.y = f2bf(acc[i][j][1]);
                o.z = f2bf(acc[i][j][2]);
                o.w = f2bf(acc[i][j][3]);
                *(ushort4*)(VtP + ((long)b * 1024 + e) * 2048 + s) = o;
            }
        }
    } else {
        #pragma unroll
        for (int i = 0; i < 4; i++) {
            #pragma unroll
            for (int j = 0; j < 4; j++) {
                #pragma unroll
                for (int r4 = 0; r4 < 4; r4++) {
                    int row = m0 + wr + i * 16 + quad * 4 + r4;
                    int col = n0 + wc + j * 16 + l16;
                    float val = acc[i][j][r4] * alpha;
                    if constexpr (sizeof(OutT) == 2)
                        C[(long)row * ldc + col] = f2bf(val);
                    else
                        C[(long)row * ldc + col] = val;
                }
            }
        }
    }
}

// ---------------------------------------------------------------------------
extern "C" void kernel_launch(void* const* d_in, const int* in_sizes, int n_in,
                              void* d_out, int out_size, void* d_ws, size_t ws_size,
                              hipStream_t stream) {
    const float* x  = (const float*)d_in[0];
    const float* Wq = (const float*)d_in[1];
    const float* Wk = (const float*)d_in[2];
    const float* Wv = (const float*)d_in[3];
    float* out = (float*)d_out;

    const int Bn = 4, S = 2048, E = 1024;
    const long MS = (long)Bn * S;              // 8192 total rows
    const int  N3 = 3 * E;                     // 3072

    // workspace layout (bf16)
    char* ws = (char*)d_ws;
    uint16_t* xb    = (uint16_t*)ws;  ws += (size_t)MS * E * 2;        // 16 MB
    uint16_t* wqkvb = (uint16_t*)ws;  ws += (size_t)N3 * E * 2;        //  6 MB
    uint16_t* QKb   = (uint16_t*)ws;  ws += (size_t)MS * 2048 * 2;     // 32 MB (Q|K, ld=2048)
    uint16_t* Vt    = (uint16_t*)ws;  ws += (size_t)Bn * E * S * 2;    // 16 MB
    uint16_t* Pb    = (uint16_t*)ws;  ws += (size_t)Bn * S * S * 2;    // 32 MB

    dim3 blk(256);

    // 1) fused cast to bf16 (x + stacked [Wq;Wk;Wv])
    {
        int NX4 = (int)(MS * E / 4);            // 2097152
        int NW4 = E * E / 4;                    // 262144
        int tot = NX4 + 3 * NW4;
        cast_all<<<dim3((tot + 255) / 256), blk, 0, stream>>>(
            x, Wq, Wk, Wv, xb, wqkvb, NX4, NW4);
    }

    // 2) fused QKV: cols [0,2048) -> QKb (ld 2048); cols [2048,3072) -> Vt
    //    transposed (Vt[b][e][s])
    {
        int gx = N3 / BN, gy = (int)(MS / BM);   // 24 x 64
        gemm_nt<uint16_t><<<dim3(gx * gy), blk, 0, stream>>>(
            xb, wqkvb, QKb, gx, gy, E, E, 2048, E, 1.f, 0, 0, 0,
            Vt, 2048);
    }

    // 3) scores = (Q K^T) / sqrt(E) per batch, bf16 out
    {
        int gx = S / BN, gy = S / BM;            // 16 x 16, z=4
        gemm_nt<uint16_t><<<dim3(gx * gy * Bn), blk, 0, stream>>>(
            QKb, QKb + 1024, Pb, gx, gy, 2048, 2048, S, E, 0.03125f,
            (long)S * 2048, (long)S * 2048, (long)S * S,
            nullptr, 0);
    }

    // 4) softmax rows in place (4*2048 rows of 2048)
    softmax_rows<<<dim3(Bn * S), blk, 0, stream>>>(Pb);

    // 5) out = P * Vt^T  (M=2048, N=1024, K=2048 per batch), fp32 out
    {
        int gx = E / BN, gy = S / BM;            // 8 x 16, z=4
        gemm_nt<float><<<dim3(gx * gy * Bn), blk, 0, stream>>>(
            Pb, Vt, out, gx, gy, S, S, E, S, 1.f,
            (long)S * S, (long)E * S, (long)S * E,
            nullptr, 0);
    }
}